// Round 16
// baseline (2322.815 us; speedup 1.0000x reference)
//
#include <hip/hip_runtime.h>
#include <hip/hip_bf16.h>

typedef _Float16 half8 __attribute__((ext_vector_type(8)));
typedef float floatx4 __attribute__((ext_vector_type(4)));

__device__ __constant__ float NF4_TAB[16] = {
    -1.0f, -0.6961928009986877f, -0.5250730514526367f, -0.39491748809814453f,
    -0.28444138169288635f, -0.18477343022823334f, -0.09105003625154495f, 0.0f,
    0.07958029955625534f, 0.16093020141124725f, 0.24611230194568634f,
    0.33791524171829224f, 0.44070982933044434f, 0.5626170039176941f,
    0.7229568362236023f, 1.0f};

typedef __attribute__((address_space(3))) void lds_t;
typedef __attribute__((address_space(1))) void gbl_t;

__device__ __forceinline__ void gload16(const void* g, void* l) {
  __builtin_amdgcn_global_load_lds((gbl_t*)g, (lds_t*)l, 16, 0, 0);
}

#define FENCE() asm volatile("" ::: "memory")

// ---------------- x f32 -> f16 ----------------
__global__ void cvt_f32_to_f16(const float* __restrict__ in,
                               _Float16* __restrict__ out, int total8) {
  int stride = gridDim.x * blockDim.x;
  for (int i = blockIdx.x * blockDim.x + threadIdx.x; i < total8; i += stride) {
    long e = (long)i * 8;
    const float4* ip = reinterpret_cast<const float4*>(in + e);
    float4 a = ip[0], b = ip[1];
    half8 o;
    o[0] = (_Float16)a.x; o[1] = (_Float16)a.y;
    o[2] = (_Float16)a.z; o[3] = (_Float16)a.w;
    o[4] = (_Float16)b.x; o[5] = (_Float16)b.y;
    o[6] = (_Float16)b.z; o[7] = (_Float16)b.w;
    *reinterpret_cast<half8*>(out + e) = o;
  }
}

// ---------------- NF4 dequant: codes[R,C] + scales[R,C/64] -> f16 [R,C] ----
__global__ void dequant_nf4(const int* __restrict__ codes,
                            const float* __restrict__ scales,
                            _Float16* __restrict__ out,
                            int total8, int C, int CB) {
  __shared__ float lut[16];
  if (threadIdx.x < 16) lut[threadIdx.x] = NF4_TAB[threadIdx.x];
  __syncthreads();
  int stride = gridDim.x * blockDim.x;
  for (int i = blockIdx.x * blockDim.x + threadIdx.x; i < total8; i += stride) {
    long e = (long)i * 8;
    int row = (int)(e / C);
    int col = (int)(e - (long)row * C);
    float sc = scales[row * CB + (col >> 6)];
    const int4* cp = reinterpret_cast<const int4*>(codes + e);
    int4 c0 = cp[0];
    int4 c1 = cp[1];
    half8 o;
    o[0] = (_Float16)(lut[c0.x & 15] * sc);
    o[1] = (_Float16)(lut[c0.y & 15] * sc);
    o[2] = (_Float16)(lut[c0.z & 15] * sc);
    o[3] = (_Float16)(lut[c0.w & 15] * sc);
    o[4] = (_Float16)(lut[c1.x & 15] * sc);
    o[5] = (_Float16)(lut[c1.y & 15] * sc);
    o[6] = (_Float16)(lut[c1.z & 15] * sc);
    o[7] = (_Float16)(lut[c1.w & 15] * sc);
    *reinterpret_cast<half8*>(out + e) = o;
  }
}

// =====================================================================
// gemm256x128: 256x128 tile, BK=32, 8 waves (2Mx4N), wave tile 128x32.
// OCCUPANCY EXPERIMENT for gate/up: 72 KB LDS (3-ring x 24 KB) ->
// 2 blocks/CU (was 1 at 128 KB). Down-GEMM runs ~90% of the ds_read
// ceiling with the 256^2 kernel; gate/up stall ABOVE the serial
// LDS+MFMA sum -> latency/occupancy symptom; independent co-resident
// blocks absorb barrier/vmcnt stalls (m114/m97 mechanism).
// Sync template = R11's validated 2-phase ring (parameter change only):
//   P0: read a[0..3]+b[0..1] (6 rds), stage A(t+2) (2 gloads), 8 MFMA
//   P1: read a[4..7] (4 rds),        stage B(t+2) (1 gload),  8 MFMA
// Ring: tile tau in buf tau%3; buffer = A slab [256][32] @0 (8192 f16),
// B slab [128][32] @8192 (4096 f16). Ledger: P1(t)-end vmcnt(3)
// certifies tile t+1 (A(t+2)x2+B(t+2)x1 newer, in flight; never 0
// mid-loop); tail kt==NT-2 -> vmcnt(0). WAR: buf(t+2)%3 holds t-1;
// A slab last read P1(t-1) < stage P0(t) (1 barrier); B slab last
// read P0(t-1) < stage P1(t) (3 barriers).
// Chunk-XOR swizzle (phys chunk = logical ^ ((row>>1)&3)): 0 conflicts.
// Rect XCD walk: xcd=bid&7, bm=4*xcd+(j&3), bn=j>>2 (bijective).
// EPI: 0 = f16 store; 1 = GH[idx]=silu(g_staged)*acc (in-place).
// =====================================================================
template <int K, int N, int EPI>
__global__ __launch_bounds__(512, 4) void gemm256x128(
    const _Float16* __restrict__ A,
    const _Float16* __restrict__ B,
    _Float16* __restrict__ GH) {
  constexpr int NT = K / 32;
  constexpr int NBC = N / 128;
  __shared__ __align__(16) _Float16 lds[3 * 12288];  // 72 KB

  const int t = threadIdx.x;       // 0..511
  const int lane = t & 63;
  const int wave = t >> 6;
  const int wm = wave >> 2;        // 0..1
  const int wn = wave & 3;         // 0..3

  // rectangular per-XCD walk (NBM=32=8 XCDs x 4; j < 4*NBC)
  const int xcd = blockIdx.x & 7;
  const int j = blockIdx.x >> 3;
  const int bm = 4 * xcd + (j & 3);
  const int bn = j >> 2;

  // staging (linear LDS dest, pre-permuted global src)
  const int lc = (t & 3) ^ ((t >> 3) & 3);
  const _Float16* gA = A + ((long)bm * 256 + (t >> 2)) * K + lc * 8;
  const _Float16* gB = B + ((long)bn * 128 + (t >> 2)) * K + lc * 8;
  const long rstep = (long)128 * K;
  const int dst = t * 8;  // f16 units (A: +4096 round 1; B slab: 4096 f16)

  // fragment read offsets
  const int rA = wm * 128 + (lane & 15);
  const int rB = wn * 32 + (lane & 15);
  const int ckA = ((lane >> 4) ^ ((rA >> 1) & 3)) * 8;  // h(r+16i)==h(r)
  const int ckB = ((lane >> 4) ^ ((rB >> 1) & 3)) * 8;
  const int offA = rA * 32 + ckA;          // + i*512
  const int offB = 8192 + rB * 32 + ckB;   // + j*512

#define STAGE_A(dbuf) \
  gload16(gA, lds + (dbuf) * 12288 + dst); \
  gload16(gA + rstep, lds + (dbuf) * 12288 + dst + 4096); gA += 32;
#define STAGE_B(dbuf) \
  gload16(gB, lds + (dbuf) * 12288 + 8192 + dst); gB += 32;

  // ---- prologue: stage tiles 0 -> buf0, 1 -> buf1 (6 loads) ----
  STAGE_A(0); STAGE_B(0);
  STAGE_A(1); STAGE_B(1);
  asm volatile("s_waitcnt vmcnt(3)" ::: "memory");  // tile 0 landed
  __builtin_amdgcn_s_barrier();
  FENCE();

  floatx4 acc[8][2] = {};

  for (int kt = 0; kt < NT; ++kt) {
    const _Float16* lb = lds + (kt % 3) * 12288;
    const int s2 = (kt + 2) % 3;
    const bool st = (kt + 2 < NT);

    half8 a[4], b[2];

    // ---- P0: read a[0..3]+b[0..1]; stage A(t+2); 8 MFMA rows 0-3 ----
#pragma unroll
    for (int i = 0; i < 4; ++i)
      a[i] = *reinterpret_cast<const half8*>(&lb[offA + i * 512]);
    b[0] = *reinterpret_cast<const half8*>(&lb[offB]);
    b[1] = *reinterpret_cast<const half8*>(&lb[offB + 512]);
    if (st) { STAGE_A(s2); }
    __builtin_amdgcn_s_barrier();
    FENCE();
    __builtin_amdgcn_s_setprio(1);
#pragma unroll
    for (int i = 0; i < 4; ++i) {
      acc[i][0] = __builtin_amdgcn_mfma_f32_16x16x32_f16(a[i], b[0], acc[i][0], 0, 0, 0);
      acc[i][1] = __builtin_amdgcn_mfma_f32_16x16x32_f16(a[i], b[1], acc[i][1], 0, 0, 0);
    }
    __builtin_amdgcn_s_setprio(0);
    __builtin_amdgcn_s_barrier();
    FENCE();

    // ---- P1: read a[4..7]; stage B(t+2); certify t+1; 8 MFMA rows 4-7 ----
#pragma unroll
    for (int i = 0; i < 4; ++i)
      a[i] = *reinterpret_cast<const half8*>(&lb[offA + (4 + i) * 512]);
    if (st) { STAGE_B(s2); }
    if (kt < NT - 2)       { asm volatile("s_waitcnt vmcnt(3)" ::: "memory"); }
    else if (kt == NT - 2) { asm volatile("s_waitcnt vmcnt(0)" ::: "memory"); }
    __builtin_amdgcn_s_barrier();
    FENCE();
    __builtin_amdgcn_s_setprio(1);
#pragma unroll
    for (int i = 0; i < 4; ++i) {
      acc[4 + i][0] = __builtin_amdgcn_mfma_f32_16x16x32_f16(a[i], b[0], acc[4 + i][0], 0, 0, 0);
      acc[4 + i][1] = __builtin_amdgcn_mfma_f32_16x16x32_f16(a[i], b[1], acc[4 + i][1], 0, 0, 0);
    }
    __builtin_amdgcn_s_setprio(0);
    __builtin_amdgcn_s_barrier();
    FENCE();
  }
#undef STAGE_A
#undef STAGE_B

  // ---- epilogue ----
  const int r0 = bm * 256 + wm * 128 + (lane >> 4) * 4;
  const int c0 = bn * 128 + wn * 32 + (lane & 15);

  if (EPI == 1) {
    // coalesced LDS-staged g read: 256x128 f16 tile = 64 KB <= 72 KB LDS
    _Float16* lg = lds;
    const _Float16* gsrc = GH + (long)(bm * 256) * N + bn * 128;
#pragma unroll
    for (int r = 0; r < 8; ++r) {
      const int row = r * 32 + (t >> 4);
      const int col = (t & 15) * 8;
      gload16(gsrc + (long)row * N + col, lg + r * 4096 + t * 8);
    }
    asm volatile("s_waitcnt vmcnt(0)" ::: "memory");
    __builtin_amdgcn_s_barrier();
    FENCE();
    const int lr0 = wm * 128 + (lane >> 4) * 4;
    const int lc0 = wn * 32 + (lane & 15);
#pragma unroll
    for (int i = 0; i < 8; ++i) {
#pragma unroll
      for (int j2 = 0; j2 < 2; ++j2) {
#pragma unroll
        for (int ii = 0; ii < 4; ++ii) {
          const long idx = (long)(r0 + i * 16 + ii) * N + (c0 + j2 * 16);
          float u = acc[i][j2][ii];
          float g = (float)lg[(lr0 + i * 16 + ii) * 128 + (lc0 + j2 * 16)];
          GH[idx] = (_Float16)(g / (1.0f + __expf(-g)) * u);
        }
      }
    }
  } else {
#pragma unroll
    for (int i = 0; i < 8; ++i) {
#pragma unroll
      for (int j2 = 0; j2 < 2; ++j2) {
#pragma unroll
        for (int ii = 0; ii < 4; ++ii) {
          const long idx = (long)(r0 + i * 16 + ii) * N + (c0 + j2 * 16);
          GH[idx] = (_Float16)acc[i][j2][ii];
        }
      }
    }
  }
}

// =====================================================================
// gemm256: BANKED R13 256x256 kernel, UNCHANGED — used for down-GEMM
// (measured at ~90% of the ds_read_b128 ceiling; do not disturb).
// =====================================================================
template <int K, int N, int EPI>
__global__ __launch_bounds__(512, 2) void gemm256(
    const _Float16* __restrict__ A,
    const _Float16* __restrict__ B,
    _Float16* __restrict__ GH,
    float* __restrict__ OUT) {
  constexpr int NT = K / 64;
  constexpr int NBC = N / 256;
  __shared__ __align__(16) _Float16 lds[2 * 32768];  // 128 KB

  const int t = threadIdx.x;
  const int lane = t & 63;
  const int wave = t >> 6;
  const int wm = wave >> 2;
  const int wn = wave & 3;

  const int xcd = blockIdx.x & 7;
  const int j = blockIdx.x >> 3;
  const int bm = 4 * xcd + (j & 3);
  const int bn = j >> 2;

  const int lc = (t & 3) ^ ((t >> 3) & 3);
  const _Float16* gA = A + ((long)bm * 256 + (t >> 2)) * K + lc * 8;
  const _Float16* gB = B + ((long)bn * 256 + (t >> 2)) * K + lc * 8;
  const long rstep = (long)128 * K;
  const int dst = t * 8;

  const int rA = wm * 128 + (lane & 15);
  const int rB = wn * 64 + (lane & 15);
  const int ckA = ((lane >> 4) ^ ((rA >> 1) & 3)) * 8;
  const int ckB = ((lane >> 4) ^ ((rB >> 1) & 3)) * 8;
  const int offA = rA * 32 + ckA;
  const int offB = 16384 + rB * 32 + ckB;

#define STAGE_SLOT(gp, slab, koff, dbuf)                                   \
  gload16((gp) + (koff), lds + (dbuf) * 32768 + (slab) + dst);             \
  gload16((gp) + (koff) + rstep, lds + (dbuf) * 32768 + (slab) + dst + 4096);

  STAGE_SLOT(gA, 0, 0, 0);
  STAGE_SLOT(gB, 16384, 0, 0);
  STAGE_SLOT(gA, 8192, 32, 0);
  STAGE_SLOT(gB, 24576, 32, 0);
  gA += 64; gB += 64;
  asm volatile("s_waitcnt vmcnt(4)" ::: "memory");
  __builtin_amdgcn_s_barrier();
  FENCE();

  floatx4 acc[8][4] = {};

  for (int kt = 0; kt < NT; ++kt) {
    const int cb = kt & 1;
    const int sbuf = cb ^ 1;
    const _Float16* lb = lds + cb * 32768;
    const bool st = (kt + 1 < NT);
    const bool last = (kt == NT - 1);

    half8 a[8], b[2];

#pragma unroll
    for (int i = 0; i < 8; ++i)
      a[i] = *reinterpret_cast<const half8*>(&lb[offA + i * 512]);
    b[0] = *reinterpret_cast<const half8*>(&lb[offB]);
    b[1] = *reinterpret_cast<const half8*>(&lb[offB + 512]);
    if (st) { STAGE_SLOT(gA, 0, 0, sbuf); }
    __builtin_amdgcn_s_barrier();
    FENCE();
    __builtin_amdgcn_s_setprio(1);
#pragma unroll
    for (int i = 0; i < 8; ++i) {
      acc[i][0] = __builtin_amdgcn_mfma_f32_16x16x32_f16(a[i], b[0], acc[i][0], 0, 0, 0);
      acc[i][1] = __builtin_amdgcn_mfma_f32_16x16x32_f16(a[i], b[1], acc[i][1], 0, 0, 0);
    }
    __builtin_amdgcn_s_setprio(0);
    __builtin_amdgcn_s_barrier();
    FENCE();

    b[0] = *reinterpret_cast<const half8*>(&lb[offB + 2 * 512]);
    b[1] = *reinterpret_cast<const half8*>(&lb[offB + 3 * 512]);
    if (st) { STAGE_SLOT(gB, 16384, 0, sbuf); }
    if (last) { asm volatile("s_waitcnt vmcnt(0)" ::: "memory"); }
    else      { asm volatile("s_waitcnt vmcnt(4)" ::: "memory"); }
    __builtin_amdgcn_s_barrier();
    FENCE();
    __builtin_amdgcn_s_setprio(1);
#pragma unroll
    for (int i = 0; i < 8; ++i) {
      acc[i][2] = __builtin_amdgcn_mfma_f32_16x16x32_f16(a[i], b[0], acc[i][2], 0, 0, 0);
      acc[i][3] = __builtin_amdgcn_mfma_f32_16x16x32_f16(a[i], b[1], acc[i][3], 0, 0, 0);
    }
    __builtin_amdgcn_s_setprio(0);
    __builtin_amdgcn_s_barrier();
    FENCE();

#pragma unroll
    for (int i = 0; i < 8; ++i)
      a[i] = *reinterpret_cast<const half8*>(&lb[8192 + offA + i * 512]);
    b[0] = *reinterpret_cast<const half8*>(&lb[8192 + offB]);
    b[1] = *reinterpret_cast<const half8*>(&lb[8192 + offB + 512]);
    if (st) { STAGE_SLOT(gA, 8192, 32, sbuf); }
    __builtin_amdgcn_s_barrier();
    FENCE();
    __builtin_amdgcn_s_setprio(1);
#pragma unroll
    for (int i = 0; i < 8; ++i) {
      acc[i][0] = __builtin_amdgcn_mfma_f32_16x16x32_f16(a[i], b[0], acc[i][0], 0, 0, 0);
      acc[i][1] = __builtin_amdgcn_mfma_f32_16x16x32_f16(a[i], b[1], acc[i][1], 0, 0, 0);
    }
    __builtin_amdgcn_s_setprio(0);
    __builtin_amdgcn_s_barrier();
    FENCE();

    b[0] = *reinterpret_cast<const half8*>(&lb[8192 + offB + 2 * 512]);
    b[1] = *reinterpret_cast<const half8*>(&lb[8192 + offB + 3 * 512]);
    if (st) { STAGE_SLOT(gB, 24576, 32, sbuf); gA += 64; gB += 64; }
    if (!last) { asm volatile("s_waitcnt vmcnt(4)" ::: "memory"); }
    __builtin_amdgcn_s_barrier();
    FENCE();
    __builtin_amdgcn_s_setprio(1);
#pragma unroll
    for (int i = 0; i < 8; ++i) {
      acc[i][2] = __builtin_amdgcn_mfma_f32_16x16x32_f16(a[i], b[0], acc[i][2], 0, 0, 0);
      acc[i][3] = __builtin_amdgcn_mfma_f32_16x16x32_f16(a[i], b[1], acc[i][3], 0, 0, 0);
    }
    __builtin_amdgcn_s_setprio(0);
    __builtin_amdgcn_s_barrier();
    FENCE();
  }
#undef STAGE_SLOT

  const int r0 = bm * 256 + wm * 128 + (lane >> 4) * 4;
  const int c0 = bn * 256 + wn * 64 + (lane & 15);
#pragma unroll
  for (int i = 0; i < 8; ++i) {
#pragma unroll
    for (int j2 = 0; j2 < 4; ++j2) {
#pragma unroll
      for (int ii = 0; ii < 4; ++ii) {
        const long idx = (long)(r0 + i * 16 + ii) * N + (c0 + j2 * 16);
        if (EPI == 0) {
          GH[idx] = (_Float16)acc[i][j2][ii];
        } else {
          OUT[idx] = acc[i][j2][ii];
        }
      }
    }
  }
}

extern "C" void kernel_launch(void* const* d_in, const int* in_sizes, int n_in,
                              void* d_out, int out_size, void* d_ws, size_t ws_size,
                              hipStream_t stream) {
  const float* x           = (const float*)d_in[0];
  const int*   gate_codes  = (const int*)d_in[1];
  const float* gate_scales = (const float*)d_in[2];
  const int*   up_codes    = (const int*)d_in[3];
  const float* up_scales   = (const float*)d_in[4];
  const int*   down_codes  = (const int*)d_in[5];
  const float* down_scales = (const float*)d_in[6];
  float* out = (float*)d_out;

  const long T = 8192, HD = 4096, M = 11008;

  // ws layout (fp16): x16 [T,HD] 67MB | W [M,HD] 90MB (reused 3x) | gh [T,M] 180MB
  char* ws = (char*)d_ws;
  _Float16* x16 = (_Float16*)ws;
  _Float16* W   = (_Float16*)(ws + T * HD * 2);
  _Float16* gh  = (_Float16*)(ws + T * HD * 2 + M * HD * 2);

  cvt_f32_to_f16<<<2048, 256, 0, stream>>>(x, x16, (int)(T * HD / 8));

  // gate: g = x @ Wg^T  -> gh (f16)   [256x128 tile, 2 blocks/CU]
  dequant_nf4<<<2048, 256, 0, stream>>>(gate_codes, gate_scales, W,
                                        (int)(M * HD / 8), (int)HD, (int)(HD / 64));
  gemm256x128<4096, 11008, 0><<<(8192 / 256) * (11008 / 128), 512, 0, stream>>>(
      x16, W, gh);

  // up + SwiGLU: gh = silu(gh) * (x @ Wu^T)   (in-place)
  dequant_nf4<<<2048, 256, 0, stream>>>(up_codes, up_scales, W,
                                        (int)(M * HD / 8), (int)HD, (int)(HD / 64));
  gemm256x128<4096, 11008, 1><<<(8192 / 256) * (11008 / 128), 512, 0, stream>>>(
      x16, W, gh);

  // down: out = gh @ Wd^T  (f32)   [banked 256x256 kernel, at roofline]
  dequant_nf4<<<2048, 256, 0, stream>>>(down_codes, down_scales, W,
                                        (int)(HD * M / 8), (int)M, (int)(M / 64));
  gemm256<11008, 4096, 2><<<(8192 / 256) * (4096 / 256), 512, 0, stream>>>(
      gh, W, nullptr, out);
}

// Round 17
// 2225.362 us; speedup vs baseline: 1.0438x; 1.0438x over previous
//
#include <hip/hip_runtime.h>
#include <hip/hip_bf16.h>

typedef _Float16 half8 __attribute__((ext_vector_type(8)));
typedef float floatx4 __attribute__((ext_vector_type(4)));

__device__ __constant__ float NF4_TAB[16] = {
    -1.0f, -0.6961928009986877f, -0.5250730514526367f, -0.39491748809814453f,
    -0.28444138169288635f, -0.18477343022823334f, -0.09105003625154495f, 0.0f,
    0.07958029955625534f, 0.16093020141124725f, 0.24611230194568634f,
    0.33791524171829224f, 0.44070982933044434f, 0.5626170039176941f,
    0.7229568362236023f, 1.0f};

typedef __attribute__((address_space(3))) void lds_t;
typedef __attribute__((address_space(1))) void gbl_t;

__device__ __forceinline__ void gload16(const void* g, void* l) {
  __builtin_amdgcn_global_load_lds((gbl_t*)g, (lds_t*)l, 16, 0, 0);
}

#define FENCE() asm volatile("" ::: "memory")

// ---------------- x f32 -> f16, PADDED row stride OS ----------------
__global__ void cvt_f32_to_f16_pad(const float* __restrict__ in,
                                   _Float16* __restrict__ out,
                                   int total8, int C8, int OS) {
  int stride = gridDim.x * blockDim.x;
  for (int i = blockIdx.x * blockDim.x + threadIdx.x; i < total8; i += stride) {
    int row = i / C8;
    int col = (i - row * C8) * 8;
    const float4* ip = reinterpret_cast<const float4*>(in + (long)row * (C8 * 8) + col);
    float4 a = ip[0], b = ip[1];
    half8 o;
    o[0] = (_Float16)a.x; o[1] = (_Float16)a.y;
    o[2] = (_Float16)a.z; o[3] = (_Float16)a.w;
    o[4] = (_Float16)b.x; o[5] = (_Float16)b.y;
    o[6] = (_Float16)b.z; o[7] = (_Float16)b.w;
    *reinterpret_cast<half8*>(out + (long)row * OS + col) = o;
  }
}

// ---- NF4 dequant: codes[R,C] + scales[R,C/64] -> f16 [R][OS-strided] ----
__global__ void dequant_nf4(const int* __restrict__ codes,
                            const float* __restrict__ scales,
                            _Float16* __restrict__ out,
                            int total8, int C, int CB, int OS) {
  __shared__ float lut[16];
  if (threadIdx.x < 16) lut[threadIdx.x] = NF4_TAB[threadIdx.x];
  __syncthreads();
  int stride = gridDim.x * blockDim.x;
  for (int i = blockIdx.x * blockDim.x + threadIdx.x; i < total8; i += stride) {
    long e = (long)i * 8;
    int row = (int)(e / C);
    int col = (int)(e - (long)row * C);
    float sc = scales[row * CB + (col >> 6)];
    const int4* cp = reinterpret_cast<const int4*>(codes + e);
    int4 c0 = cp[0];
    int4 c1 = cp[1];
    half8 o;
    o[0] = (_Float16)(lut[c0.x & 15] * sc);
    o[1] = (_Float16)(lut[c0.y & 15] * sc);
    o[2] = (_Float16)(lut[c0.z & 15] * sc);
    o[3] = (_Float16)(lut[c0.w & 15] * sc);
    o[4] = (_Float16)(lut[c1.x & 15] * sc);
    o[5] = (_Float16)(lut[c1.y & 15] * sc);
    o[6] = (_Float16)(lut[c1.z & 15] * sc);
    o[7] = (_Float16)(lut[c1.w & 15] * sc);
    *reinterpret_cast<half8*>(out + (long)row * OS + col) = o;
  }
}

// =====================================================================
// 256x256 GEMM, BK=64, 8 waves (2Mx4N), per-wave 128x64 output.
// BANKED R13 structure (validated 4x through graph replay) + R17's one
// change: operand row stride LD is a template param, decoupled from K.
// WHY: identical kernel runs 2830 cy/K-tile on down (strides 22016 B =
// 2^9*43) vs 5670 on gate/up (strides 8192 B = pure pow2). A staging
// burst reads 256 rows at the row pitch; an 8 KB pitch maps all rows to
// the same HBM-channel/L2-set group -> address camping throttles supply
// (explains the ~860 TF plateau across 6 schedule variants). Gate/up
// operands are ws-internal, so we pad to LD=4160 f16 (8320 B = 2^7*65).
// Pad is never read (max staged col 4096 <= 4160) -> deterministic.
//  - R7 staging/ledger: 4 phases/K-tile (reads 10/2/10/2), one stage
//    slot per phase; counted vmcnt(4) at P1/P3; never 0 mid-loop.
//  - R12 rectangular per-XCD walk (FETCH -2.6x, measured).
//  - R13 EPI=1 coalesced LDS-staged g read (up -60us, measured).
// Slabs per 64KB buffer: A@k0=0, A@k1=8192, B@k0=16384, B@k1=24576.
// Chunk-XOR swizzle (phys chunk = logical ^ ((row>>1)&3)): 0 conflicts.
// EPI: 0 = f16 store; 1 = GH[idx]=silu(g_staged)*acc (in-place); 2 = f32.
// =====================================================================
template <int K, int LD, int N, int EPI>
__global__ __launch_bounds__(512, 2) void gemm256(
    const _Float16* __restrict__ A,
    const _Float16* __restrict__ B,
    _Float16* __restrict__ GH,
    float* __restrict__ OUT) {
  constexpr int NT = K / 64;
  constexpr int NBC = N / 256;
  __shared__ __align__(16) _Float16 lds[2 * 32768];  // 128 KB

  const int t = threadIdx.x;       // 0..511
  const int lane = t & 63;
  const int wave = t >> 6;
  const int wm = wave >> 2;        // 0..1
  const int wn = wave & 3;         // 0..3

  // rectangular per-XCD walk (bijective: NBM=32=8 XCDs x 4, j<4*NBC)
  const int xcd = blockIdx.x & 7;
  const int j = blockIdx.x >> 3;
  const int bm = 4 * xcd + (j & 3);
  const int bn = j >> 2;

  // staging: round r in {0,1}: row=(t>>2)+128r, chunk lc=(t&3)^((t>>3)&3)
  const int lc = (t & 3) ^ ((t >> 3) & 3);
  const _Float16* gA = A + ((long)bm * 256 + (t >> 2)) * LD + lc * 8;
  const _Float16* gB = B + ((long)bn * 256 + (t >> 2)) * LD + lc * 8;
  const long rstep = (long)128 * LD;
  const int dst = t * 8;  // f16 units; +4096 for round 1 (wave-linear)

  // fragment read offsets (f16 units within buffer)
  const int rA = wm * 128 + (lane & 15);
  const int rB = wn * 64 + (lane & 15);
  const int ckA = ((lane >> 4) ^ ((rA >> 1) & 3)) * 8;  // h(r+16i)==h(r)
  const int ckB = ((lane >> 4) ^ ((rB >> 1) & 3)) * 8;
  const int offA = rA * 32 + ckA;           // + i*512 (+8192 for kk1)
  const int offB = 16384 + rB * 32 + ckB;   // + j*512 (+8192 for kk1)

#define STAGE_SLOT(gp, slab, koff, dbuf)                                   \
  gload16((gp) + (koff), lds + (dbuf) * 32768 + (slab) + dst);             \
  gload16((gp) + (koff) + rstep, lds + (dbuf) * 32768 + (slab) + dst + 4096);

  // ---- prologue: stage tile 0 -> buf0, order A0,B0,A1,B1 ----
  STAGE_SLOT(gA, 0, 0, 0);
  STAGE_SLOT(gB, 16384, 0, 0);
  STAGE_SLOT(gA, 8192, 32, 0);
  STAGE_SLOT(gB, 24576, 32, 0);
  gA += 64; gB += 64;
  asm volatile("s_waitcnt vmcnt(4)" ::: "memory");  // A0,B0(0) done
  __builtin_amdgcn_s_barrier();
  FENCE();

  floatx4 acc[8][4] = {};

  for (int kt = 0; kt < NT; ++kt) {
    const int cb = kt & 1;
    const int sbuf = cb ^ 1;
    const _Float16* lb = lds + cb * 32768;
    const bool st = (kt + 1 < NT);
    const bool last = (kt == NT - 1);

    half8 a[8], b[2];

    // ---- P0: read a@kk0 x8 + b[0..1]@kk0; stage A0(t+1) ----
#pragma unroll
    for (int i = 0; i < 8; ++i)
      a[i] = *reinterpret_cast<const half8*>(&lb[offA + i * 512]);
    b[0] = *reinterpret_cast<const half8*>(&lb[offB]);
    b[1] = *reinterpret_cast<const half8*>(&lb[offB + 512]);
    if (st) { STAGE_SLOT(gA, 0, 0, sbuf); }
    __builtin_amdgcn_s_barrier();
    FENCE();
    __builtin_amdgcn_s_setprio(1);
#pragma unroll
    for (int i = 0; i < 8; ++i) {
      acc[i][0] = __builtin_amdgcn_mfma_f32_16x16x32_f16(a[i], b[0], acc[i][0], 0, 0, 0);
      acc[i][1] = __builtin_amdgcn_mfma_f32_16x16x32_f16(a[i], b[1], acc[i][1], 0, 0, 0);
    }
    __builtin_amdgcn_s_setprio(0);
    __builtin_amdgcn_s_barrier();
    FENCE();

    // ---- P1: read b[2..3]@kk0; stage B0(t+1); certify A1,B1(t) ----
    b[0] = *reinterpret_cast<const half8*>(&lb[offB + 2 * 512]);
    b[1] = *reinterpret_cast<const half8*>(&lb[offB + 3 * 512]);
    if (st) { STAGE_SLOT(gB, 16384, 0, sbuf); }
    if (last) { asm volatile("s_waitcnt vmcnt(0)" ::: "memory"); }
    else      { asm volatile("s_waitcnt vmcnt(4)" ::: "memory"); }
    __builtin_amdgcn_s_barrier();
    FENCE();
    __builtin_amdgcn_s_setprio(1);
#pragma unroll
    for (int i = 0; i < 8; ++i) {
      acc[i][2] = __builtin_amdgcn_mfma_f32_16x16x32_f16(a[i], b[0], acc[i][2], 0, 0, 0);
      acc[i][3] = __builtin_amdgcn_mfma_f32_16x16x32_f16(a[i], b[1], acc[i][3], 0, 0, 0);
    }
    __builtin_amdgcn_s_setprio(0);
    __builtin_amdgcn_s_barrier();
    FENCE();

    // ---- P2: read a@kk1 x8 + b[0..1]@kk1; stage A1(t+1) ----
#pragma unroll
    for (int i = 0; i < 8; ++i)
      a[i] = *reinterpret_cast<const half8*>(&lb[8192 + offA + i * 512]);
    b[0] = *reinterpret_cast<const half8*>(&lb[8192 + offB]);
    b[1] = *reinterpret_cast<const half8*>(&lb[8192 + offB + 512]);
    if (st) { STAGE_SLOT(gA, 8192, 32, sbuf); }
    __builtin_amdgcn_s_barrier();
    FENCE();
    __builtin_amdgcn_s_setprio(1);
#pragma unroll
    for (int i = 0; i < 8; ++i) {
      acc[i][0] = __builtin_amdgcn_mfma_f32_16x16x32_f16(a[i], b[0], acc[i][0], 0, 0, 0);
      acc[i][1] = __builtin_amdgcn_mfma_f32_16x16x32_f16(a[i], b[1], acc[i][1], 0, 0, 0);
    }
    __builtin_amdgcn_s_setprio(0);
    __builtin_amdgcn_s_barrier();
    FENCE();

    // ---- P3: read b[2..3]@kk1; stage B1(t+1); certify A0,B0(t+1) ----
    b[0] = *reinterpret_cast<const half8*>(&lb[8192 + offB + 2 * 512]);
    b[1] = *reinterpret_cast<const half8*>(&lb[8192 + offB + 3 * 512]);
    if (st) { STAGE_SLOT(gB, 24576, 32, sbuf); gA += 64; gB += 64; }
    if (!last) { asm volatile("s_waitcnt vmcnt(4)" ::: "memory"); }
    __builtin_amdgcn_s_barrier();
    FENCE();
    __builtin_amdgcn_s_setprio(1);
#pragma unroll
    for (int i = 0; i < 8; ++i) {
      acc[i][2] = __builtin_amdgcn_mfma_f32_16x16x32_f16(a[i], b[0], acc[i][2], 0, 0, 0);
      acc[i][3] = __builtin_amdgcn_mfma_f32_16x16x32_f16(a[i], b[1], acc[i][3], 0, 0, 0);
    }
    __builtin_amdgcn_s_setprio(0);
    __builtin_amdgcn_s_barrier();
    FENCE();
  }
#undef STAGE_SLOT

  // ---- epilogue ----
  const int r0 = bm * 256 + wm * 128 + (lane >> 4) * 4;
  const int c0 = bn * 256 + wn * 64 + (lane & 15);

  if (EPI == 1) {
    // Coalesced LDS-staged g read (scattered read was ~4x line waste)
    _Float16* lg = lds;  // [256][256] f16 = 128 KB = whole LDS
    const _Float16* gsrc = GH + (long)(bm * 256) * N + bn * 256;
#pragma unroll
    for (int r = 0; r < 16; ++r) {
      const int row = r * 16 + (t >> 5);
      const int col = (t & 31) * 8;
      gload16(gsrc + (long)row * N + col, lg + r * 4096 + t * 8);
    }
    asm volatile("s_waitcnt vmcnt(0)" ::: "memory");
    __builtin_amdgcn_s_barrier();
    FENCE();
    const int lr0 = wm * 128 + (lane >> 4) * 4;
    const int lc0 = wn * 64 + (lane & 15);
#pragma unroll
    for (int i = 0; i < 8; ++i) {
#pragma unroll
      for (int j2 = 0; j2 < 4; ++j2) {
#pragma unroll
        for (int ii = 0; ii < 4; ++ii) {
          const long idx = (long)(r0 + i * 16 + ii) * N + (c0 + j2 * 16);
          float u = acc[i][j2][ii];
          float g = (float)lg[(lr0 + i * 16 + ii) * 256 + (lc0 + j2 * 16)];
          GH[idx] = (_Float16)(g / (1.0f + __expf(-g)) * u);
        }
      }
    }
  } else {
#pragma unroll
    for (int i = 0; i < 8; ++i) {
#pragma unroll
      for (int j2 = 0; j2 < 4; ++j2) {
#pragma unroll
        for (int ii = 0; ii < 4; ++ii) {
          const long idx = (long)(r0 + i * 16 + ii) * N + (c0 + j2 * 16);
          if (EPI == 0) {
            GH[idx] = (_Float16)acc[i][j2][ii];
          } else {
            OUT[idx] = acc[i][j2][ii];
          }
        }
      }
    }
  }
}

extern "C" void kernel_launch(void* const* d_in, const int* in_sizes, int n_in,
                              void* d_out, int out_size, void* d_ws, size_t ws_size,
                              hipStream_t stream) {
  const float* x           = (const float*)d_in[0];
  const int*   gate_codes  = (const int*)d_in[1];
  const float* gate_scales = (const float*)d_in[2];
  const int*   up_codes    = (const int*)d_in[3];
  const float* up_scales   = (const float*)d_in[4];
  const int*   down_codes  = (const int*)d_in[5];
  const float* down_scales = (const float*)d_in[6];
  float* out = (float*)d_out;

  const long T = 8192, HD = 4096, M = 11008;
  const long LDP = 4160;  // padded stride for gate/up operands (8320 B = 2^7*65)

  // ws: x16 [T,4160] 68MB | W [M,4160] 92MB (gate/up padded; down uses
  // stride 11008 within same buffer) | gh [T,M] 180MB
  char* ws = (char*)d_ws;
  _Float16* x16 = (_Float16*)ws;
  _Float16* W   = (_Float16*)(ws + T * LDP * 2);
  _Float16* gh  = (_Float16*)(ws + T * LDP * 2 + M * LDP * 2);

  cvt_f32_to_f16_pad<<<2048, 256, 0, stream>>>(x, x16, (int)(T * HD / 8),
                                               (int)(HD / 8), (int)LDP);

  // gate: g = x @ Wg^T  -> gh (f16)   [padded strides 4160]
  dequant_nf4<<<2048, 256, 0, stream>>>(gate_codes, gate_scales, W,
                                        (int)(M * HD / 8), (int)HD, (int)(HD / 64),
                                        (int)LDP);
  gemm256<4096, 4160, 11008, 0><<<(8192 / 256) * (11008 / 256), 512, 0, stream>>>(
      x16, W, gh, nullptr);

  // up + SwiGLU: gh = silu(gh) * (x @ Wu^T)   (in-place)
  dequant_nf4<<<2048, 256, 0, stream>>>(up_codes, up_scales, W,
                                        (int)(M * HD / 8), (int)HD, (int)(HD / 64),
                                        (int)LDP);
  gemm256<4096, 4160, 11008, 1><<<(8192 / 256) * (11008 / 256), 512, 0, stream>>>(
      x16, W, gh, nullptr);

  // down: out = gh @ Wd^T (f32)  [strides 11008 = 2^9*43, already non-pow2]
  dequant_nf4<<<2048, 256, 0, stream>>>(down_codes, down_scales, W,
                                        (int)(HD * M / 8), (int)M, (int)(M / 64),
                                        (int)M);
  gemm256<11008, 11008, 4096, 2><<<(8192 / 256) * (4096 / 256), 512, 0, stream>>>(
      gh, W, nullptr, out);
}

// Round 18
// 2107.636 us; speedup vs baseline: 1.1021x; 1.0559x over previous
//
#include <hip/hip_runtime.h>
#include <hip/hip_bf16.h>

typedef _Float16 half8 __attribute__((ext_vector_type(8)));
typedef float floatx4 __attribute__((ext_vector_type(4)));

__device__ __constant__ float NF4_TAB[16] = {
    -1.0f, -0.6961928009986877f, -0.5250730514526367f, -0.39491748809814453f,
    -0.28444138169288635f, -0.18477343022823334f, -0.09105003625154495f, 0.0f,
    0.07958029955625534f, 0.16093020141124725f, 0.24611230194568634f,
    0.33791524171829224f, 0.44070982933044434f, 0.5626170039176941f,
    0.7229568362236023f, 1.0f};

typedef __attribute__((address_space(3))) void lds_t;
typedef __attribute__((address_space(1))) void gbl_t;

__device__ __forceinline__ void gload16(const void* g, void* l) {
  __builtin_amdgcn_global_load_lds((gbl_t*)g, (lds_t*)l, 16, 0, 0);
}

#define FENCE() asm volatile("" ::: "memory")

// ---------------- x f32 -> f16 (row stride OS) ----------------
__global__ void cvt_f32_to_f16_pad(const float* __restrict__ in,
                                   _Float16* __restrict__ out,
                                   int total8, int C8, int OS) {
  int stride = gridDim.x * blockDim.x;
  for (int i = blockIdx.x * blockDim.x + threadIdx.x; i < total8; i += stride) {
    int row = i / C8;
    int col = (i - row * C8) * 8;
    const float4* ip = reinterpret_cast<const float4*>(in + (long)row * (C8 * 8) + col);
    float4 a = ip[0], b = ip[1];
    half8 o;
    o[0] = (_Float16)a.x; o[1] = (_Float16)a.y;
    o[2] = (_Float16)a.z; o[3] = (_Float16)a.w;
    o[4] = (_Float16)b.x; o[5] = (_Float16)b.y;
    o[6] = (_Float16)b.z; o[7] = (_Float16)b.w;
    *reinterpret_cast<half8*>(out + (long)row * OS + col) = o;
  }
}

// ---- NF4 dequant: codes[R,C] + scales[R,C/64] -> f16 [R][OS-strided] ----
__global__ void dequant_nf4(const int* __restrict__ codes,
                            const float* __restrict__ scales,
                            _Float16* __restrict__ out,
                            int total8, int C, int CB, int OS) {
  __shared__ float lut[16];
  if (threadIdx.x < 16) lut[threadIdx.x] = NF4_TAB[threadIdx.x];
  __syncthreads();
  int stride = gridDim.x * blockDim.x;
  for (int i = blockIdx.x * blockDim.x + threadIdx.x; i < total8; i += stride) {
    long e = (long)i * 8;
    int row = (int)(e / C);
    int col = (int)(e - (long)row * C);
    float sc = scales[row * CB + (col >> 6)];
    const int4* cp = reinterpret_cast<const int4*>(codes + e);
    int4 c0 = cp[0];
    int4 c1 = cp[1];
    half8 o;
    o[0] = (_Float16)(lut[c0.x & 15] * sc);
    o[1] = (_Float16)(lut[c0.y & 15] * sc);
    o[2] = (_Float16)(lut[c0.z & 15] * sc);
    o[3] = (_Float16)(lut[c0.w & 15] * sc);
    o[4] = (_Float16)(lut[c1.x & 15] * sc);
    o[5] = (_Float16)(lut[c1.y & 15] * sc);
    o[6] = (_Float16)(lut[c1.z & 15] * sc);
    o[7] = (_Float16)(lut[c1.w & 15] * sc);
    *reinterpret_cast<half8*>(out + (long)row * OS + col) = o;
  }
}

// =====================================================================
// FUSED gate+up GEMM: 256(M) x 128(N per matrix) tile, BK=64, 8 waves
// (2Mx4N), per-wave output 128x32 for EACH of G,U. Computes
//   gh = silu(x@Wg^T) * (x@Wu^T) in one pass (no gh round-trip:
// saves gate's 180MB store + up's 180MB g-reread + up's epilogue).
// Same per-tile resources as the banked R13 kernel: 24 ds_read_b128 +
// 64 MFMA + 8 staged loads (2/phase) per thread per K-tile; identical
// counted-vmcnt ledger shape (validated 5x through graph replay).
// LDS per 64KB buffer (f16 units): A@k0=0, A@k1=8192 ([256][32] ea),
//   G@k0=16384, G@k1=20480, U@k0=24576, U@k1=28672 ([128][32] ea).
// Phases (reads / MFMA / stage-slot for t+1):
//   P0: a@k0 x8 + bg@k0 x2 -> accG (16) ; stage A0
//   P1: bu@k0 x2 (a held)  -> accU (16) ; stage G@k0+U@k0
//   P2: a@k1 x8 + bg@k1 x2 -> accG (16) ; stage A1
//   P3: bu@k1 x2 (a held)  -> accU (16) ; stage G@k1+U@k1
// Ledger (2 loads/phase, never 0 mid-loop):
//   P1(t) vmcnt(4) certifies A1,Gk1,Uk1(t)   [staged P2,P3(t-1); newer:
//     P0,P1(t) = 4 in flight]  -> read at P2,P3(t) after barrier. OK
//   P3(t) vmcnt(4) certifies A0,Gk0,Uk0(t+1) [staged P0,P1(t)] -> read
//     at P0,P1(t+1). OK.  Tail: P1(NT-1) vmcnt(0).
// WAR: every sbuf slab's overwrite is >=4 barriers after its last read
//   (A0/Gk0: read P0(t-1); Uk0: P1(t-1); A1/Gk1: P2(t-1); Uk1: P3(t-1)).
// Chunk-XOR swizzle (phys chunk = logical ^ ((row>>1)&3)): 0 conflicts.
// Rect XCD walk: xcd=bid&7, bm=4*xcd+(j&3), bn=j>>2 (bijective, NBM=32).
// =====================================================================
template <int K, int LD, int N>
__global__ __launch_bounds__(512, 2) void gemm_fused(
    const _Float16* __restrict__ A,
    const _Float16* __restrict__ G,
    const _Float16* __restrict__ U,
    _Float16* __restrict__ GH) {
  constexpr int NT = K / 64;
  __shared__ __align__(16) _Float16 lds[2 * 32768];  // 128 KB

  const int t = threadIdx.x;       // 0..511
  const int lane = t & 63;
  const int wave = t >> 6;
  const int wm = wave >> 2;        // 0..1
  const int wn = wave & 3;         // 0..3

  const int xcd = blockIdx.x & 7;
  const int j = blockIdx.x >> 3;
  const int bm = 4 * xcd + (j & 3);
  const int bn = j >> 2;           // 0..85

  // staging (linear LDS dest, pre-permuted global src)
  const int lc = (t & 3) ^ ((t >> 3) & 3);
  const _Float16* gA = A + ((long)bm * 256 + (t >> 2)) * LD + lc * 8;
  const _Float16* gG = G + ((long)bn * 128 + (t >> 2)) * LD + lc * 8;
  const _Float16* gU = U + ((long)bn * 128 + (t >> 2)) * LD + lc * 8;
  const long rstep = (long)128 * LD;
  const int dst = t * 8;  // f16 units

  // fragment read offsets
  const int rA = wm * 128 + (lane & 15);
  const int rB = wn * 32 + (lane & 15);
  const int ckA = ((lane >> 4) ^ ((rA >> 1) & 3)) * 8;  // h(r+16i)==h(r)
  const int ckB = ((lane >> 4) ^ ((rB >> 1) & 3)) * 8;
  const int offA = rA * 32 + ckA;            // + i*512 (+8192 for k1)
  const int offBG = 16384 + rB * 32 + ckB;   // + j2*512 (+4096 for k1)
  const int offBU = 24576 + rB * 32 + ckB;   // + j2*512 (+4096 for k1)

  // ---- prologue: stage tile 0 -> buf0 in slot order A0,(Gk0,Uk0),A1,(Gk1,Uk1)
  gload16(gA, lds + dst);
  gload16(gA + rstep, lds + dst + 4096);
  gload16(gG, lds + 16384 + dst);
  gload16(gU, lds + 24576 + dst);
  gload16(gA + 32, lds + 8192 + dst);
  gload16(gA + 32 + rstep, lds + 8192 + dst + 4096);
  gload16(gG + 32, lds + 20480 + dst);
  gload16(gU + 32, lds + 28672 + dst);
  gA += 64; gG += 64; gU += 64;
  asm volatile("s_waitcnt vmcnt(4)" ::: "memory");  // A0,Gk0,Uk0(0) done
  __builtin_amdgcn_s_barrier();
  FENCE();

  floatx4 accG[8][2] = {};
  floatx4 accU[8][2] = {};

  for (int kt = 0; kt < NT; ++kt) {
    const int cb = kt & 1;
    const int sbuf = cb ^ 1;
    const _Float16* lb = lds + cb * 32768;
    _Float16* sb = lds + sbuf * 32768;
    const bool st = (kt + 1 < NT);
    const bool last = (kt == NT - 1);

    half8 a[8], b[2];

    // ---- P0: read a@k0 x8 + bg@k0 x2; stage A0(t+1); accG ----
#pragma unroll
    for (int i = 0; i < 8; ++i)
      a[i] = *reinterpret_cast<const half8*>(&lb[offA + i * 512]);
    b[0] = *reinterpret_cast<const half8*>(&lb[offBG]);
    b[1] = *reinterpret_cast<const half8*>(&lb[offBG + 512]);
    if (st) { gload16(gA, sb + dst); gload16(gA + rstep, sb + dst + 4096); }
    __builtin_amdgcn_s_barrier();
    FENCE();
    __builtin_amdgcn_s_setprio(1);
#pragma unroll
    for (int i = 0; i < 8; ++i) {
      accG[i][0] = __builtin_amdgcn_mfma_f32_16x16x32_f16(a[i], b[0], accG[i][0], 0, 0, 0);
      accG[i][1] = __builtin_amdgcn_mfma_f32_16x16x32_f16(a[i], b[1], accG[i][1], 0, 0, 0);
    }
    __builtin_amdgcn_s_setprio(0);
    __builtin_amdgcn_s_barrier();
    FENCE();

    // ---- P1: read bu@k0 x2 (a held); stage Gk0,Uk0(t+1); cert A1,Gk1,Uk1(t) ----
    b[0] = *reinterpret_cast<const half8*>(&lb[offBU]);
    b[1] = *reinterpret_cast<const half8*>(&lb[offBU + 512]);
    if (st) { gload16(gG, sb + 16384 + dst); gload16(gU, sb + 24576 + dst); }
    if (last) { asm volatile("s_waitcnt vmcnt(0)" ::: "memory"); }
    else      { asm volatile("s_waitcnt vmcnt(4)" ::: "memory"); }
    __builtin_amdgcn_s_barrier();
    FENCE();
    __builtin_amdgcn_s_setprio(1);
#pragma unroll
    for (int i = 0; i < 8; ++i) {
      accU[i][0] = __builtin_amdgcn_mfma_f32_16x16x32_f16(a[i], b[0], accU[i][0], 0, 0, 0);
      accU[i][1] = __builtin_amdgcn_mfma_f32_16x16x32_f16(a[i], b[1], accU[i][1], 0, 0, 0);
    }
    __builtin_amdgcn_s_setprio(0);
    __builtin_amdgcn_s_barrier();
    FENCE();

    // ---- P2: read a@k1 x8 + bg@k1 x2; stage A1(t+1); accG ----
#pragma unroll
    for (int i = 0; i < 8; ++i)
      a[i] = *reinterpret_cast<const half8*>(&lb[8192 + offA + i * 512]);
    b[0] = *reinterpret_cast<const half8*>(&lb[offBG + 4096]);
    b[1] = *reinterpret_cast<const half8*>(&lb[offBG + 4096 + 512]);
    if (st) { gload16(gA + 32, sb + 8192 + dst); gload16(gA + 32 + rstep, sb + 8192 + dst + 4096); }
    __builtin_amdgcn_s_barrier();
    FENCE();
    __builtin_amdgcn_s_setprio(1);
#pragma unroll
    for (int i = 0; i < 8; ++i) {
      accG[i][0] = __builtin_amdgcn_mfma_f32_16x16x32_f16(a[i], b[0], accG[i][0], 0, 0, 0);
      accG[i][1] = __builtin_amdgcn_mfma_f32_16x16x32_f16(a[i], b[1], accG[i][1], 0, 0, 0);
    }
    __builtin_amdgcn_s_setprio(0);
    __builtin_amdgcn_s_barrier();
    FENCE();

    // ---- P3: read bu@k1 x2 (a held); stage Gk1,Uk1(t+1); cert A0,Gk0,Uk0(t+1) ----
    b[0] = *reinterpret_cast<const half8*>(&lb[offBU + 4096]);
    b[1] = *reinterpret_cast<const half8*>(&lb[offBU + 4096 + 512]);
    if (st) {
      gload16(gG + 32, sb + 20480 + dst);
      gload16(gU + 32, sb + 28672 + dst);
      gA += 64; gG += 64; gU += 64;
    }
    if (!last) { asm volatile("s_waitcnt vmcnt(4)" ::: "memory"); }
    __builtin_amdgcn_s_barrier();
    FENCE();
    __builtin_amdgcn_s_setprio(1);
#pragma unroll
    for (int i = 0; i < 8; ++i) {
      accU[i][0] = __builtin_amdgcn_mfma_f32_16x16x32_f16(a[i], b[0], accU[i][0], 0, 0, 0);
      accU[i][1] = __builtin_amdgcn_mfma_f32_16x16x32_f16(a[i], b[1], accU[i][1], 0, 0, 0);
    }
    __builtin_amdgcn_s_setprio(0);
    __builtin_amdgcn_s_barrier();
    FENCE();
  }

  // ---- epilogue: h = silu(g)*u in registers, single f16 store ----
  const int r0 = bm * 256 + wm * 128 + (lane >> 4) * 4;
  const int c0 = bn * 128 + wn * 32 + (lane & 15);
#pragma unroll
  for (int i = 0; i < 8; ++i) {
#pragma unroll
    for (int j2 = 0; j2 < 2; ++j2) {
#pragma unroll
      for (int ii = 0; ii < 4; ++ii) {
        const long idx = (long)(r0 + i * 16 + ii) * N + (c0 + j2 * 16);
        float g = accG[i][j2][ii];
        float u = accU[i][j2][ii];
        GH[idx] = (_Float16)(g / (1.0f + __expf(-g)) * u);
      }
    }
  }
}

// =====================================================================
// gemm256: banked R13 256x256 kernel (validated), used for down-GEMM.
// =====================================================================
template <int K, int LD, int N, int EPI>
__global__ __launch_bounds__(512, 2) void gemm256(
    const _Float16* __restrict__ A,
    const _Float16* __restrict__ B,
    _Float16* __restrict__ GH,
    float* __restrict__ OUT) {
  constexpr int NT = K / 64;
  constexpr int NBC = N / 256;
  __shared__ __align__(16) _Float16 lds[2 * 32768];  // 128 KB

  const int t = threadIdx.x;
  const int lane = t & 63;
  const int wave = t >> 6;
  const int wm = wave >> 2;
  const int wn = wave & 3;

  const int xcd = blockIdx.x & 7;
  const int j = blockIdx.x >> 3;
  const int bm = 4 * xcd + (j & 3);
  const int bn = j >> 2;

  const int lc = (t & 3) ^ ((t >> 3) & 3);
  const _Float16* gA = A + ((long)bm * 256 + (t >> 2)) * LD + lc * 8;
  const _Float16* gB = B + ((long)bn * 256 + (t >> 2)) * LD + lc * 8;
  const long rstep = (long)128 * LD;
  const int dst = t * 8;

  const int rA = wm * 128 + (lane & 15);
  const int rB = wn * 64 + (lane & 15);
  const int ckA = ((lane >> 4) ^ ((rA >> 1) & 3)) * 8;
  const int ckB = ((lane >> 4) ^ ((rB >> 1) & 3)) * 8;
  const int offA = rA * 32 + ckA;
  const int offB = 16384 + rB * 32 + ckB;

#define STAGE_SLOT(gp, slab, koff, dbuf)                                   \
  gload16((gp) + (koff), lds + (dbuf) * 32768 + (slab) + dst);             \
  gload16((gp) + (koff) + rstep, lds + (dbuf) * 32768 + (slab) + dst + 4096);

  STAGE_SLOT(gA, 0, 0, 0);
  STAGE_SLOT(gB, 16384, 0, 0);
  STAGE_SLOT(gA, 8192, 32, 0);
  STAGE_SLOT(gB, 24576, 32, 0);
  gA += 64; gB += 64;
  asm volatile("s_waitcnt vmcnt(4)" ::: "memory");
  __builtin_amdgcn_s_barrier();
  FENCE();

  floatx4 acc[8][4] = {};

  for (int kt = 0; kt < NT; ++kt) {
    const int cb = kt & 1;
    const int sbuf = cb ^ 1;
    const _Float16* lb = lds + cb * 32768;
    const bool st = (kt + 1 < NT);
    const bool last = (kt == NT - 1);

    half8 a[8], b[2];

#pragma unroll
    for (int i = 0; i < 8; ++i)
      a[i] = *reinterpret_cast<const half8*>(&lb[offA + i * 512]);
    b[0] = *reinterpret_cast<const half8*>(&lb[offB]);
    b[1] = *reinterpret_cast<const half8*>(&lb[offB + 512]);
    if (st) { STAGE_SLOT(gA, 0, 0, sbuf); }
    __builtin_amdgcn_s_barrier();
    FENCE();
    __builtin_amdgcn_s_setprio(1);
#pragma unroll
    for (int i = 0; i < 8; ++i) {
      acc[i][0] = __builtin_amdgcn_mfma_f32_16x16x32_f16(a[i], b[0], acc[i][0], 0, 0, 0);
      acc[i][1] = __builtin_amdgcn_mfma_f32_16x16x32_f16(a[i], b[1], acc[i][1], 0, 0, 0);
    }
    __builtin_amdgcn_s_setprio(0);
    __builtin_amdgcn_s_barrier();
    FENCE();

    b[0] = *reinterpret_cast<const half8*>(&lb[offB + 2 * 512]);
    b[1] = *reinterpret_cast<const half8*>(&lb[offB + 3 * 512]);
    if (st) { STAGE_SLOT(gB, 16384, 0, sbuf); }
    if (last) { asm volatile("s_waitcnt vmcnt(0)" ::: "memory"); }
    else      { asm volatile("s_waitcnt vmcnt(4)" ::: "memory"); }
    __builtin_amdgcn_s_barrier();
    FENCE();
    __builtin_amdgcn_s_setprio(1);
#pragma unroll
    for (int i = 0; i < 8; ++i) {
      acc[i][2] = __builtin_amdgcn_mfma_f32_16x16x32_f16(a[i], b[0], acc[i][2], 0, 0, 0);
      acc[i][3] = __builtin_amdgcn_mfma_f32_16x16x32_f16(a[i], b[1], acc[i][3], 0, 0, 0);
    }
    __builtin_amdgcn_s_setprio(0);
    __builtin_amdgcn_s_barrier();
    FENCE();

#pragma unroll
    for (int i = 0; i < 8; ++i)
      a[i] = *reinterpret_cast<const half8*>(&lb[8192 + offA + i * 512]);
    b[0] = *reinterpret_cast<const half8*>(&lb[8192 + offB]);
    b[1] = *reinterpret_cast<const half8*>(&lb[8192 + offB + 512]);
    if (st) { STAGE_SLOT(gA, 8192, 32, sbuf); }
    __builtin_amdgcn_s_barrier();
    FENCE();
    __builtin_amdgcn_s_setprio(1);
#pragma unroll
    for (int i = 0; i < 8; ++i) {
      acc[i][0] = __builtin_amdgcn_mfma_f32_16x16x32_f16(a[i], b[0], acc[i][0], 0, 0, 0);
      acc[i][1] = __builtin_amdgcn_mfma_f32_16x16x32_f16(a[i], b[1], acc[i][1], 0, 0, 0);
    }
    __builtin_amdgcn_s_setprio(0);
    __builtin_amdgcn_s_barrier();
    FENCE();

    b[0] = *reinterpret_cast<const half8*>(&lb[8192 + offB + 2 * 512]);
    b[1] = *reinterpret_cast<const half8*>(&lb[8192 + offB + 3 * 512]);
    if (st) { STAGE_SLOT(gB, 24576, 32, sbuf); gA += 64; gB += 64; }
    if (!last) { asm volatile("s_waitcnt vmcnt(4)" ::: "memory"); }
    __builtin_amdgcn_s_barrier();
    FENCE();
    __builtin_amdgcn_s_setprio(1);
#pragma unroll
    for (int i = 0; i < 8; ++i) {
      acc[i][2] = __builtin_amdgcn_mfma_f32_16x16x32_f16(a[i], b[0], acc[i][2], 0, 0, 0);
      acc[i][3] = __builtin_amdgcn_mfma_f32_16x16x32_f16(a[i], b[1], acc[i][3], 0, 0, 0);
    }
    __builtin_amdgcn_s_setprio(0);
    __builtin_amdgcn_s_barrier();
    FENCE();
  }
#undef STAGE_SLOT

  const int r0 = bm * 256 + wm * 128 + (lane >> 4) * 4;
  const int c0 = bn * 256 + wn * 64 + (lane & 15);
#pragma unroll
  for (int i = 0; i < 8; ++i) {
#pragma unroll
    for (int j2 = 0; j2 < 4; ++j2) {
#pragma unroll
      for (int ii = 0; ii < 4; ++ii) {
        const long idx = (long)(r0 + i * 16 + ii) * N + (c0 + j2 * 16);
        if (EPI == 0) {
          GH[idx] = (_Float16)acc[i][j2][ii];
        } else {
          OUT[idx] = acc[i][j2][ii];
        }
      }
    }
  }
}

extern "C" void kernel_launch(void* const* d_in, const int* in_sizes, int n_in,
                              void* d_out, int out_size, void* d_ws, size_t ws_size,
                              hipStream_t stream) {
  const float* x           = (const float*)d_in[0];
  const int*   gate_codes  = (const int*)d_in[1];
  const float* gate_scales = (const float*)d_in[2];
  const int*   up_codes    = (const int*)d_in[3];
  const float* up_scales   = (const float*)d_in[4];
  const int*   down_codes  = (const int*)d_in[5];
  const float* down_scales = (const float*)d_in[6];
  float* out = (float*)d_out;

  const long T = 8192, HD = 4096, M = 11008;

  // ws: x16 [T,HD] 67MB | Wg [M,HD] 90MB | Wu [M,HD] 90MB | gh [T,M] 180MB
  // (down-weights reuse Wg's slot after the fused kernel completes)
  char* ws = (char*)d_ws;
  _Float16* x16 = (_Float16*)ws;
  _Float16* Wg  = (_Float16*)(ws + T * HD * 2);
  _Float16* Wu  = (_Float16*)(ws + T * HD * 2 + M * HD * 2);
  _Float16* gh  = (_Float16*)(ws + T * HD * 2 + 2 * M * HD * 2);

  cvt_f32_to_f16_pad<<<2048, 256, 0, stream>>>(x, x16, (int)(T * HD / 8),
                                               (int)(HD / 8), (int)HD);
  dequant_nf4<<<2048, 256, 0, stream>>>(gate_codes, gate_scales, Wg,
                                        (int)(M * HD / 8), (int)HD, (int)(HD / 64),
                                        (int)HD);
  dequant_nf4<<<2048, 256, 0, stream>>>(up_codes, up_scales, Wu,
                                        (int)(M * HD / 8), (int)HD, (int)(HD / 64),
                                        (int)HD);

  // fused gate+up+SwiGLU: gh = silu(x@Wg^T) * (x@Wu^T)
  gemm_fused<4096, 4096, 11008><<<(8192 / 256) * (11008 / 128), 512, 0, stream>>>(
      x16, Wg, Wu, gh);

  // down: out = gh @ Wd^T (f32)
  dequant_nf4<<<2048, 256, 0, stream>>>(down_codes, down_scales, Wg,
                                        (int)(HD * M / 8), (int)M, (int)(M / 64),
                                        (int)M);
  gemm256<11008, 11008, 4096, 2><<<(8192 / 256) * (4096 / 256), 512, 0, stream>>>(
      gh, Wg, nullptr, out);
}